// Round 6
// baseline (10726.112 us; speedup 1.0000x reference)
//
#include <hip/hip_runtime.h>
#include <math.h>

#define B_ 64
#define S_ 512
#define I_ 300
#define H_ 512
#define T_ 25
#define KXP_ 320   // x K padded to 10 MFMA K-tiles of 32

typedef short bf16x8 __attribute__((ext_vector_type(8)));
typedef float f32x4  __attribute__((ext_vector_type(4)));

// Shared slot->k convention for MFMA fragments (A and B use the SAME map, so
// any bijection is self-consistent): elem j of the short8, lane l:
//   k = 16*(j>>2) + 4*((l>>4)&3) + (j&3)
__host__ __device__ __forceinline__ int kmap(int l, int j) {
    return 16 * (j >> 2) + 4 * ((l >> 4) & 3) + (j & 3);
}

// ---------------- workspace layout (float elements) ----------------
static constexpr size_t SZ_XT    = (size_t)S_ * KXP_ * B_;      // 10,485,760
static constexpr size_t OFS_XTF  = 0;                            // xT fwd [s][k][b]
static constexpr size_t OFS_XTB  = OFS_XTF + SZ_XT;              // xT bwd (reversed)
static constexpr size_t OFS_WHF  = OFS_XTB + SZ_XT;              // h A-frags (shorts)
static constexpr size_t SZ_WHF_S = (size_t)2 * 128 * 2 * 8 * 2 * 64 * 8;  // 4,194,304 shorts
static constexpr size_t OFS_WXF  = OFS_WHF + SZ_WHF_S / 2;       // x A-frags (shorts)
static constexpr size_t SZ_WXF_S = (size_t)2 * 128 * 2 * 5 * 2 * 64 * 8;  // 2,621,440 shorts
static constexpr size_t OFS_ZB   = OFS_WXF + SZ_WXF_S / 2;       // zero h for s=0
static constexpr size_t OFS_YF   = OFS_ZB + (size_t)2 * H_ * B_;
static constexpr size_t SZ_Y     = (size_t)S_ * H_ * B_;         // 16,777,216
static constexpr size_t OFS_YB   = OFS_YF + SZ_Y;
static constexpr size_t SZ_L     = (size_t)B_ * S_ * T_;         // 819,200
static constexpr size_t OFS_L1   = OFS_YB + SZ_Y;
static constexpr size_t OFS_L2   = OFS_L1 + SZ_L;
static constexpr size_t OFS_LEN  = OFS_L2 + SZ_L;   // int32[64]
static constexpr size_t OFS_LLH  = OFS_LEN + 64;    // float[64]
static constexpr size_t OFS_FLG  = OFS_LLH + 64;    // int32[2*128*16] flags, 64B/line

// output layout (float elements in d_out)
static constexpr size_t OFF_LOGITS = 1;
static constexpr size_t OFF_TAGS   = 1 + SZ_L;
static constexpr size_t OFF_MASK   = OFF_TAGS + (size_t)B_ * S_;

// ---------------- small utility kernels ----------------
__global__ void k_lengths(const int* __restrict__ am, int* __restrict__ len) {
    int b = threadIdx.x;
    int sum = 0;
    for (int s = 0; s < S_; ++s) sum += am[b * S_ + s];
    len[b] = sum;
}

__global__ void k_zero(float* __restrict__ p, int n) {
    int idx = blockIdx.x * 256 + threadIdx.x;
    if (idx < n) p[idx] = 0.f;
}

// Whh -> per-(dir,ug,kh) A-fragment streams, split bf16 hi/lo.
// short idx = [((((dir*128+ug)*2+kh)*8 + kt)*2 + hilo)*64 + lane]*8 + j
// A[m][k]: m = lane&15 (row within tile, r' = uu*4+g), k = kh*256+kt*32+kmap.
__global__ void k_prep_hfrag(const float* __restrict__ whhf,
                             const float* __restrict__ whhb,
                             short* __restrict__ hf) {
    for (size_t idx = (size_t)blockIdx.x * 256 + threadIdx.x; idx < SZ_WHF_S;
         idx += (size_t)gridDim.x * 256) {
        int j = (int)(idx & 7); size_t t = idx >> 3;
        int l = (int)(t & 63); t >>= 6;
        int hilo = (int)(t & 1); t >>= 1;
        int kt = (int)(t & 7); t >>= 3;
        int kh = (int)(t & 1); t >>= 1;
        int ug = (int)(t & 127); t >>= 7;
        int dir = (int)t;
        int m = l & 15;
        int row = (m & 3) * H_ + ug * 4 + (m >> 2);   // g*H + u
        int k = kh * 256 + kt * 32 + kmap(l, j);
        float w = (dir ? whhb : whhf)[(size_t)row * H_ + k];
        unsigned u32 = __float_as_uint(w);
        float hi_f = __uint_as_float(u32 & 0xffff0000u);
        hf[idx] = hilo ? (short)(__float_as_uint(w - hi_f) >> 16)
                       : (short)(u32 >> 16);
    }
}

// W_ih -> x A-fragments (K padded 300->320 with zeros), same conventions.
__global__ void k_prep_xfrag(const float* __restrict__ wihf,
                             const float* __restrict__ wihb,
                             short* __restrict__ xf) {
    for (size_t idx = (size_t)blockIdx.x * 256 + threadIdx.x; idx < SZ_WXF_S;
         idx += (size_t)gridDim.x * 256) {
        int j = (int)(idx & 7); size_t t = idx >> 3;
        int l = (int)(t & 63); t >>= 6;
        int hilo = (int)(t & 1); t >>= 1;
        int kt = (int)(t % 5); t /= 5;
        int kh = (int)(t & 1); t >>= 1;
        int ug = (int)(t & 127); t >>= 7;
        int dir = (int)t;
        int m = l & 15;
        int row = (m & 3) * H_ + ug * 4 + (m >> 2);
        int k = kh * 160 + kt * 32 + kmap(l, j);
        float w = 0.f;
        if (k < I_) w = (dir ? wihb : wihf)[(size_t)row * I_ + k];
        unsigned u32 = __float_as_uint(w);
        float hi_f = __uint_as_float(u32 & 0xffff0000u);
        xf[idx] = hilo ? (short)(__float_as_uint(w - hi_f) >> 16)
                       : (short)(u32 >> 16);
    }
}

// x[b][s][i] -> xT[s][i(320)][b] (k-major, b-minor; rows 300..319 zeroed).
// rev variant gathers per-batch reversed rows.
__global__ __launch_bounds__(256) void k_xpose(const float* __restrict__ x,
                                               const int* __restrict__ len,
                                               float* __restrict__ xtf,
                                               float* __restrict__ xtb) {
    __shared__ int lsrc[B_];
    int s = blockIdx.x & 511, isrev = blockIdx.x >> 9;  // grid = 1024
    int tid = threadIdx.x;
    if (tid < B_) {
        int src = s;
        if (isrev) { int L = len[tid]; src = (s < L) ? (L - 1 - s) : s; }
        lsrc[tid] = src;
    }
    __syncthreads();
    float* dst = (isrev ? xtb : xtf) + (size_t)s * KXP_ * B_;
    for (int dw = tid; dw < KXP_ * B_; dw += 256) {
        int i = dw >> 6, b = dw & 63;
        dst[dw] = (i < I_) ? x[((size_t)b * S_ + lsrc[b]) * I_ + i] : 0.f;
    }
}

// ---------------- persistent BiLSTM scan: split-bf16 MFMA ----------------
// 256 blocks x 512 threads (cooperative for co-residency; NO grid.sync).
// Block = (dir, ug) owns units u=ug*4..+3 -> one 16-row M-tile in permuted
// row space r' = uu*4+g (tile holds complete gate quads -> trivial finalize).
// Wave wq = (nt = wq>>1: 16-col N-tile of b; kh = wq&1: K-half).
// Weights: A-fragments (hi+lo bf16) RESIDENT IN REGISTERS for all 512 steps
// -> zero per-step weight traffic (kills the replicated-broadcast pipe pin
// that held every previous version at ~16us/step).
// Per step/wave: x-phase (pre-wait): 40 B-loads + 15 MFMAs into D;
// h-phase (post-wait): 64 B-loads of y[s-1] + 24 MFMAs into D.
// Split-bf16: A=Ah+Al, B=Bh+Bl; D += Ah*Bh + Ah*Bl + Al*Bh (err ~2^-17).
// Sync/flag/y protocol identical to the verified round-4 kernel.
__global__ __launch_bounds__(512, 2) void k_scan(
    const short* __restrict__ whf, const short* __restrict__ wxf,
    const float* __restrict__ xtf, const float* __restrict__ xtb,
    const float* __restrict__ zb,
    float* yf, float* ybr,
    const float* __restrict__ bf, const float* __restrict__ bb,
    const int* __restrict__ len, int* __restrict__ flg)
{
    __shared__ float parts[2 * 16 * 64];   // [kh][m][b] : 8 KB
    const int dir = blockIdx.x >> 7;
    const int ug  = blockIdx.x & 127;
    const int tid = threadIdx.x;
    const int lane = tid & 63;
    const int wq = __builtin_amdgcn_readfirstlane(tid >> 6);  // 0..7
    const int nt = wq >> 1, kh = wq & 1;
    const int bcol = (nt << 4) + (lane & 15);

    // ---- A-fragments (weights) -> registers, once ----
    bf16x8 ah[8], al[8], axh[5], axl[5];
    {
        const bf16x8* hp = (const bf16x8*)whf +
            (((size_t)(dir * 128 + ug) * 2 + kh) * 8) * 128;
#pragma unroll
        for (int kt = 0; kt < 8; ++kt) {
            ah[kt] = hp[kt * 128 + lane];
            al[kt] = hp[kt * 128 + 64 + lane];
        }
        const bf16x8* xp = (const bf16x8*)wxf +
            (((size_t)(dir * 128 + ug) * 2 + kh) * 5) * 128;
#pragma unroll
        for (int kt = 0; kt < 5; ++kt) {
            axh[kt] = xp[kt * 128 + lane];
            axl[kt] = xp[kt * 128 + 64 + lane];
        }
    }

    const float* __restrict__ xta = dir ? xtb : xtf;
    float* ybase = dir ? ybr : yf;
    int* const myflag = flg + ((size_t)(dir * 128 + ug) << 4);
    // this wave consumes u in [kh*256, kh*256+256) -> producers ug' = kh*64+0..63
    const int* const fp = flg + ((size_t)(dir * 128 + kh * 64 + lane) << 4);

    // finalizer (waves 0..3 = uu) persistent state
    const int uF = (ug << 2) + wq;
    float c_reg = 0.f;
    float bi0 = 0.f, bi1 = 0.f, bi2 = 0.f, bi3 = 0.f;
    if (wq < 4) {
        const float* bias = dir ? bb : bf;
        bi0 = bias[uF]; bi1 = bias[H_ + uF];
        bi2 = bias[2 * H_ + uF]; bi3 = bias[3 * H_ + uF];
    }
    const int Lb = len[lane];

    int ko[8];
#pragma unroll
    for (int j = 0; j < 8; ++j) ko[j] = kmap(lane, j);

    for (int s = 0; s < S_; ++s) {
        f32x4 d = {0.f, 0.f, 0.f, 0.f};

        // ---- x-phase (h-independent, pre-wait) ----
        {
            const float* xs = xta + (size_t)s * (KXP_ * B_) + bcol;
            float xv[5][8];
#pragma unroll
            for (int kt = 0; kt < 5; ++kt) {
                const int k0 = kh * 160 + kt * 32;
#pragma unroll
                for (int j = 0; j < 8; ++j)
                    xv[kt][j] = xs[(size_t)(k0 + ko[j]) << 6];
            }
#pragma unroll
            for (int kt = 0; kt < 5; ++kt) {
                bf16x8 bh, bl;
#pragma unroll
                for (int j = 0; j < 8; ++j) {
                    unsigned u32 = __float_as_uint(xv[kt][j]);
                    bh[j] = (short)(u32 >> 16);
                    float hi_f = __uint_as_float(u32 & 0xffff0000u);
                    bl[j] = (short)(__float_as_uint(xv[kt][j] - hi_f) >> 16);
                }
                d = __builtin_amdgcn_mfma_f32_16x16x32_bf16(axh[kt], bh, d, 0, 0, 0);
                d = __builtin_amdgcn_mfma_f32_16x16x32_bf16(axh[kt], bl, d, 0, 0, 0);
                d = __builtin_amdgcn_mfma_f32_16x16x32_bf16(axl[kt], bh, d, 0, 0, 0);
            }
        }

        // ---- wait: this wave's 64 producers must have flagged step s ----
        if (s) {
            for (;;) {
                int v = __hip_atomic_load(fp, __ATOMIC_RELAXED,
                                          __HIP_MEMORY_SCOPE_AGENT);
                if (__all(v >= s)) break;
                __builtin_amdgcn_s_sleep(1);
            }
        }
        asm volatile("" ::: "memory");

        // ---- h-phase: plain cacheable loads of y[s-1], 2 halves x 4 K-tiles ----
        const float* hprev = s ? (ybase + ((size_t)(s - 1) << 15))  // H_*B_
                               : (zb + (dir << 15));
#pragma unroll
        for (int hf2 = 0; hf2 < 2; ++hf2) {
            float hv[4][8];
#pragma unroll
            for (int kt = 0; kt < 4; ++kt) {
                const int k0 = kh * 256 + (hf2 * 4 + kt) * 32;
#pragma unroll
                for (int j = 0; j < 8; ++j)
                    hv[kt][j] = hprev[((size_t)(k0 + ko[j]) << 6) + bcol];
            }
#pragma unroll
            for (int kt = 0; kt < 4; ++kt) {
                bf16x8 bh, bl;
#pragma unroll
                for (int j = 0; j < 8; ++j) {
                    unsigned u32 = __float_as_uint(hv[kt][j]);
                    bh[j] = (short)(u32 >> 16);
                    float hi_f = __uint_as_float(u32 & 0xffff0000u);
                    bl[j] = (short)(__float_as_uint(hv[kt][j] - hi_f) >> 16);
                }
                const int t = hf2 * 4 + kt;
                d = __builtin_amdgcn_mfma_f32_16x16x32_bf16(ah[t], bh, d, 0, 0, 0);
                d = __builtin_amdgcn_mfma_f32_16x16x32_bf16(ah[t], bl, d, 0, 0, 0);
                d = __builtin_amdgcn_mfma_f32_16x16x32_bf16(al[t], bh, d, 0, 0, 0);
            }
        }

        // ---- dump D (C/D layout: col=lane&15, row=(lane>>4)*4+reg) ----
        {
            const int m0 = (lane >> 4) << 2;
#pragma unroll
            for (int r = 0; r < 4; ++r)
                parts[(kh * 16 + m0 + r) * 64 + bcol] = d[r];
        }
        __syncthreads();

        if (wq < 4) {
            const int rb = wq << 2;   // m = uu*4 + g, uu = wq
            float g0 = bi0 + parts[(rb + 0) * 64 + lane] + parts[(16 + rb + 0) * 64 + lane];
            float g1 = bi1 + parts[(rb + 1) * 64 + lane] + parts[(16 + rb + 1) * 64 + lane];
            float g2 = bi2 + parts[(rb + 2) * 64 + lane] + parts[(16 + rb + 2) * 64 + lane];
            float g3 = bi3 + parts[(rb + 3) * 64 + lane] + parts[(16 + rb + 3) * 64 + lane];
            float ii = 1.f / (1.f + expf(-g0));
            float ff = 1.f / (1.f + expf(-g1));
            float gg = tanhf(g2);
            float oo = 1.f / (1.f + expf(-g3));
            float cn2 = ff * c_reg + ii * gg;
            float hn = oo * tanhf(cn2);
            c_reg = cn2;                       // post-length state is don't-care
            float yv = (s < Lb) ? hn : 0.f;
            __hip_atomic_store(&ybase[((size_t)(s * H_ + uF) << 6) + lane], yv,
                               __ATOMIC_RELAXED, __HIP_MEMORY_SCOPE_AGENT);
        }

        // drain y stores, block barrier, one flag store (no RMW).
        asm volatile("s_waitcnt vmcnt(0)" ::: "memory");
        __syncthreads();
        if (tid == 0)
            __hip_atomic_store(myflag, s + 1, __ATOMIC_RELAXED,
                               __HIP_MEMORY_SCOPE_AGENT);
    }
}

// ---------------- logits / CRF epilogue (unchanged, verified) ----------------
__global__ __launch_bounds__(256) void k_logits(const float* __restrict__ yf,
                                                const float* __restrict__ ybr,
                                                const float* __restrict__ wc,
                                                const float* __restrict__ bcv,
                                                float* __restrict__ L1,
                                                float* __restrict__ L2p) {
    __shared__ float smem[T_ * H_];
    int part = blockIdx.x >> 9;
    int s = blockIdx.x & 511;
    int tid = threadIdx.x;
    const float* y = part ? ybr : yf;
    float* Ldst = part ? L2p : L1;
    for (int idx = tid; idx < T_ * H_; idx += 256) {
        int t = idx >> 9;
        int h = idx & 511;
        smem[idx] = wc[(size_t)t * 1024 + part * 512 + h];
    }
    __syncthreads();
    int q = tid >> 6, b = tid & 63;
    float acc[T_];
#pragma unroll
    for (int t = 0; t < T_; ++t) acc[t] = 0.f;
    const float* yrow = y + (size_t)s * H_ * B_ + b;
    for (int h = q * 128; h < q * 128 + 128; ++h) {
        float a = yrow[(size_t)h * B_];
#pragma unroll
        for (int t = 0; t < T_; ++t) acc[t] += a * smem[t * H_ + h];
    }
    __syncthreads();
    float* pl = smem;
#pragma unroll
    for (int t = 0; t < T_; ++t) pl[(q * 64 + b) * 26 + t] = acc[t];
    __syncthreads();
    for (int idx = tid; idx < B_ * T_; idx += 256) {
        int bb2 = idx / T_;
        int t = idx - bb2 * T_;
        float v = pl[(0 * 64 + bb2) * 26 + t] + pl[(1 * 64 + bb2) * 26 + t] +
                  pl[(2 * 64 + bb2) * 26 + t] + pl[(3 * 64 + bb2) * 26 + t];
        if (!part) v += bcv[t];
        Ldst[((size_t)bb2 * S_ + s) * T_ + t] = v;
    }
}

__global__ void k_combine(const float* __restrict__ L1, const float* __restrict__ L2p,
                          const int* __restrict__ len, float* __restrict__ outlog) {
    int id = blockIdx.x * 256 + threadIdx.x;  // 32768 = B*S
    int b = id >> 9;
    int s = id & 511;
    int L = len[b];
    int sr = (s < L) ? (L - 1 - s) : s;
    const float* p1 = L1 + ((size_t)b * S_ + s) * T_;
    const float* p2 = L2p + ((size_t)b * S_ + sr) * T_;
    float* o = outlog + ((size_t)b * S_ + s) * T_;
#pragma unroll
    for (int t = 0; t < T_; ++t) o[t] = p1[t] + p2[t];
}

__global__ __launch_bounds__(64) void k_crf_nll(const float* __restrict__ em,
                                                const int* __restrict__ labels,
                                                const int* __restrict__ len,
                                                const float* __restrict__ cs,
                                                const float* __restrict__ ce,
                                                const float* __restrict__ ctr,
                                                float* __restrict__ llh) {
    int b = blockIdx.x, tid = threadIdx.x;
    __shared__ float tr[T_ * T_];
    __shared__ float sa[T_], sb[T_];
    for (int idx = tid; idx < T_ * T_; idx += 64) tr[idx] = ctr[idx];
    const float* e = em + (size_t)b * S_ * T_;
    int L = len[b];
    if (tid < T_) sa[tid] = cs[tid] + e[tid];
    __syncthreads();
    float* cur = sa;
    float* nx = sb;
    for (int t = 1; t < L; ++t) {
        if (tid < T_) {
            float m = -1e30f;
            for (int i = 0; i < T_; ++i) m = fmaxf(m, cur[i] + tr[i * T_ + tid]);
            float ssum = 0.f;
            for (int i = 0; i < T_; ++i) ssum += expf(cur[i] + tr[i * T_ + tid] - m);
            nx[tid] = m + logf(ssum) + e[(size_t)t * T_ + tid];
        }
        __syncthreads();
        float* tmp = cur; cur = nx; nx = tmp;
    }
    float part = 0.f;
    for (int t = tid; t < S_; t += 64) {
        if (t >= 1 && t < L) {
            int lp = labels[b * S_ + t - 1];
            int lc = labels[b * S_ + t];
            part += tr[lp * T_ + lc] + e[(size_t)t * T_ + lc];
        }
    }
    for (int off = 32; off; off >>= 1) part += __shfl_down(part, off, 64);
    if (tid == 0) {
        float m = -1e30f;
        for (int j = 0; j < T_; ++j) m = fmaxf(m, cur[j] + ce[j]);
        float ssum = 0.f;
        for (int j = 0; j < T_; ++j) ssum += expf(cur[j] + ce[j] - m);
        float denom = m + logf(ssum);
        int l0 = labels[b * S_];
        int lL = labels[b * S_ + L - 1];
        float num = cs[l0] + e[l0] + part + ce[lL];
        llh[b] = num - denom;
    }
}

__global__ void k_loss(const float* __restrict__ llh, const int* __restrict__ len,
                       float* __restrict__ out0) {
    int tid = threadIdx.x;
    float v = llh[tid];
    float n = (float)len[tid];
    for (int off = 32; off; off >>= 1) {
        v += __shfl_down(v, off, 64);
        n += __shfl_down(n, off, 64);
    }
    if (tid == 0) out0[0] = -(v / n);
}

__global__ __launch_bounds__(64) void k_viterbi(const float* __restrict__ em,
                                                const int* __restrict__ len,
                                                const float* __restrict__ cs,
                                                const float* __restrict__ ce,
                                                const float* __restrict__ ctr,
                                                float* __restrict__ otags,
                                                float* __restrict__ omask) {
    int b = blockIdx.x, tid = threadIdx.x;
    __shared__ float tr[T_ * T_];
    __shared__ float sa[T_], sb[T_];
    __shared__ unsigned char hist[(S_ - 1) * T_];
    __shared__ unsigned char tg[S_];
    for (int idx = tid; idx < T_ * T_; idx += 64) tr[idx] = ctr[idx];
    const float* e = em + (size_t)b * S_ * T_;
    int L = len[b];
    if (tid < T_) sa[tid] = cs[tid] + e[tid];
    __syncthreads();
    float* cur = sa;
    float* nx = sb;
    for (int t = 1; t < L; ++t) {
        if (tid < T_) {
            float best = -1e30f;
            int bi = 0;
            for (int i = 0; i < T_; ++i) {
                float v = cur[i] + tr[i * T_ + tid];
                if (v > best) { best = v; bi = i; }
            }
            nx[tid] = best + e[(size_t)t * T_ + tid];
            hist[(t - 1) * T_ + tid] = (unsigned char)bi;
        }
        __syncthreads();
        float* tmp = cur; cur = nx; nx = tmp;
    }
    if (tid == 0) {
        float best = -1e30f;
        int bt = 0;
        for (int j = 0; j < T_; ++j) {
            float v = cur[j] + ce[j];
            if (v > best) { best = v; bt = j; }
        }
        tg[S_ - 1] = (unsigned char)bt;
        for (int t = S_ - 2; t >= 0; --t) {
            if (t + 1 < L) bt = hist[t * T_ + bt];
            tg[t] = (unsigned char)bt;
        }
    }
    __syncthreads();
    for (int idx = tid; idx < S_; idx += 64) {
        otags[(size_t)b * S_ + idx] = (float)tg[idx];
        omask[(size_t)b * S_ + idx] = (idx < L) ? 1.f : 0.f;
    }
}

// ---------------- host launch ----------------
extern "C" void kernel_launch(void* const* d_in, const int* in_sizes, int n_in,
                              void* d_out, int out_size, void* d_ws, size_t ws_size,
                              hipStream_t stream) {
    const float* x    = (const float*)d_in[0];
    const float* wihf = (const float*)d_in[1];
    const float* whhf = (const float*)d_in[2];
    const float* bf   = (const float*)d_in[3];
    const float* wihb = (const float*)d_in[4];
    const float* whhb = (const float*)d_in[5];
    const float* bb   = (const float*)d_in[6];
    const float* wc   = (const float*)d_in[7];
    const float* bc   = (const float*)d_in[8];
    const float* cs   = (const float*)d_in[9];
    const float* ce   = (const float*)d_in[10];
    const float* ctr  = (const float*)d_in[11];
    const int* am     = (const int*)d_in[12];
    const int* labels = (const int*)d_in[13];

    float* ws   = (float*)d_ws;
    float* xtf  = ws + OFS_XTF;
    float* xtb  = ws + OFS_XTB;
    short* whfr = (short*)(ws + OFS_WHF);
    short* wxfr = (short*)(ws + OFS_WXF);
    float* zb   = ws + OFS_ZB;
    float* yf   = ws + OFS_YF;
    float* ybr  = ws + OFS_YB;
    float* L1p  = ws + OFS_L1;
    float* L2p  = ws + OFS_L2;
    int*   lenp = (int*)(ws + OFS_LEN);
    float* llhp = ws + OFS_LLH;
    int*   flgp = (int*)(ws + OFS_FLG);
    float* out  = (float*)d_out;

    k_lengths<<<1, 64, 0, stream>>>(am, lenp);
    k_prep_hfrag<<<2048, 256, 0, stream>>>(whhf, whhb, whfr);
    k_prep_xfrag<<<2048, 256, 0, stream>>>(wihf, wihb, wxfr);
    k_zero<<<256, 256, 0, stream>>>(zb, 2 * H_ * B_);            // s=0 h
    k_zero<<<16, 256, 0, stream>>>(ws + OFS_FLG, 2 * 128 * 16);  // flags
    k_xpose<<<1024, 256, 0, stream>>>(x, lenp, xtf, xtb);

    {
        void* kargs[] = {
            (void*)&whfr, (void*)&wxfr,
            (void*)&xtf, (void*)&xtb,
            (void*)&zb,
            (void*)&yf, (void*)&ybr,
            (void*)&bf, (void*)&bb,
            (void*)&lenp, (void*)&flgp
        };
        hipLaunchCooperativeKernel((const void*)k_scan,
                                   dim3(256), dim3(512), kargs, 0, stream);
    }

    k_logits<<<1024, 256, 0, stream>>>(yf, ybr, wc, bc, L1p, L2p);
    k_combine<<<128, 256, 0, stream>>>(L1p, L2p, lenp, out + OFF_LOGITS);
    k_crf_nll<<<64, 64, 0, stream>>>(out + OFF_LOGITS, labels, lenp, cs, ce, ctr, llhp);
    k_loss<<<1, 64, 0, stream>>>(llhp, lenp, out);
    k_viterbi<<<64, 64, 0, stream>>>(out + OFF_LOGITS, lenp, cs, ce, ctr,
                                     out + OFF_TAGS, out + OFF_MASK);
}

// Round 7
// 3668.741 us; speedup vs baseline: 2.9236x; 2.9236x over previous
//
#include <hip/hip_runtime.h>
#include <math.h>

#define B_ 64
#define S_ 512
#define I_ 300
#define H_ 512
#define T_ 25

typedef short bf16x8 __attribute__((ext_vector_type(8)));
typedef float f32x4  __attribute__((ext_vector_type(4)));

// Shared slot->k convention for MFMA fragments (A and B use the SAME map, so
// any bijection is self-consistent; verified numerically in round 6):
//   k = 16*(j>>2) + 4*((l>>4)&3) + (j&3)
__host__ __device__ __forceinline__ int kmap(int l, int j) {
    return 16 * (j >> 2) + 4 * ((l >> 4) & 3) + (j & 3);
}

// ---------------- workspace layout (float elements) ----------------
// x B-fragments: [s][dir][kh][nt][kt(5)][hilo][lane][8] shorts
static constexpr size_t SZ_XBF_S = (size_t)S_ * 2 * 2 * 4 * 5 * 2 * 64 * 8; // 41,943,040
static constexpr size_t OFS_XBF  = 0;
static constexpr size_t OFS_WHF  = OFS_XBF + SZ_XBF_S / 2;       // h A-frags (shorts)
static constexpr size_t SZ_WHF_S = (size_t)2 * 128 * 2 * 8 * 2 * 64 * 8;  // 4,194,304
static constexpr size_t OFS_WXF  = OFS_WHF + SZ_WHF_S / 2;       // x A-frags (shorts)
static constexpr size_t SZ_WXF_S = (size_t)2 * 128 * 2 * 5 * 2 * 64 * 8;  // 2,621,440
static constexpr size_t OFS_YF   = OFS_WXF + SZ_WXF_S / 2;
static constexpr size_t SZ_Y     = (size_t)S_ * H_ * B_;         // 16,777,216
static constexpr size_t OFS_YB   = OFS_YF + SZ_Y;
static constexpr size_t SZ_L     = (size_t)B_ * S_ * T_;         // 819,200
static constexpr size_t OFS_L1   = OFS_YB + SZ_Y;
static constexpr size_t OFS_L2   = OFS_L1 + SZ_L;
static constexpr size_t OFS_LEN  = OFS_L2 + SZ_L;   // int32[64]
static constexpr size_t OFS_LLH  = OFS_LEN + 64;    // float[64]
static constexpr size_t OFS_FLG  = OFS_LLH + 64;    // int32[2*128*16] flags, 64B/line

// output layout (float elements in d_out)
static constexpr size_t OFF_LOGITS = 1;
static constexpr size_t OFF_TAGS   = 1 + SZ_L;
static constexpr size_t OFF_MASK   = OFF_TAGS + (size_t)B_ * S_;

// ---------------- small utility kernels ----------------
__global__ void k_lengths(const int* __restrict__ am, int* __restrict__ len) {
    int b = threadIdx.x;
    int sum = 0;
    for (int s = 0; s < S_; ++s) sum += am[b * S_ + s];
    len[b] = sum;
}

__global__ void k_zero(float* __restrict__ p, int n) {
    int idx = blockIdx.x * 256 + threadIdx.x;
    if (idx < n) p[idx] = 0.f;
}

// Whh -> per-(dir,ug) A-fragment streams, split bf16 hi/lo (round-6 verified).
// short idx = [((((dir*128+ug)*2+kh)*8 + kt)*2 + hilo)*64 + lane]*8 + j
__global__ void k_prep_hfrag(const float* __restrict__ whhf,
                             const float* __restrict__ whhb,
                             short* __restrict__ hf) {
    for (size_t idx = (size_t)blockIdx.x * 256 + threadIdx.x; idx < SZ_WHF_S;
         idx += (size_t)gridDim.x * 256) {
        int j = (int)(idx & 7); size_t t = idx >> 3;
        int l = (int)(t & 63); t >>= 6;
        int hilo = (int)(t & 1); t >>= 1;
        int kt = (int)(t & 7); t >>= 3;
        int kh = (int)(t & 1); t >>= 1;
        int ug = (int)(t & 127); t >>= 7;
        int dir = (int)t;
        int m = l & 15;
        int row = (m & 3) * H_ + ug * 4 + (m >> 2);   // g*H + u
        int k = kh * 256 + kt * 32 + kmap(l, j);
        float w = (dir ? whhb : whhf)[(size_t)row * H_ + k];
        unsigned u32 = __float_as_uint(w);
        float hi_f = __uint_as_float(u32 & 0xffff0000u);
        hf[idx] = hilo ? (short)(__float_as_uint(w - hi_f) >> 16)
                       : (short)(u32 >> 16);
    }
}

// W_ih -> x A-fragments (K padded 300->320 with zeros), round-6 verified.
__global__ void k_prep_xfrag(const float* __restrict__ wihf,
                             const float* __restrict__ wihb,
                             short* __restrict__ xf) {
    for (size_t idx = (size_t)blockIdx.x * 256 + threadIdx.x; idx < SZ_WXF_S;
         idx += (size_t)gridDim.x * 256) {
        int j = (int)(idx & 7); size_t t = idx >> 3;
        int l = (int)(t & 63); t >>= 6;
        int hilo = (int)(t & 1); t >>= 1;
        int kt = (int)(t % 5); t /= 5;
        int kh = (int)(t & 1); t >>= 1;
        int ug = (int)(t & 127); t >>= 7;
        int dir = (int)t;
        int m = l & 15;
        int row = (m & 3) * H_ + ug * 4 + (m >> 2);
        int k = kh * 160 + kt * 32 + kmap(l, j);
        float w = 0.f;
        if (k < I_) w = (dir ? wihb : wihf)[(size_t)row * I_ + k];
        unsigned u32 = __float_as_uint(w);
        float hi_f = __uint_as_float(u32 & 0xffff0000u);
        xf[idx] = hilo ? (short)(__float_as_uint(w - hi_f) >> 16)
                       : (short)(u32 >> 16);
    }
}

// x -> B-fragments, precomputed per (s, dir, kh, nt, kt, hilo): kills the
// scan's per-step scatter loads + split VALU for x; consumer loads are
// contiguous dwordx4 shared by all 128 ug-blocks of a dir (L2-friendly).
// short idx = [(((((s*2+dir)*2+kh)*4+nt)*5 + kt)*2 + hilo)*64 + lane]*8 + j
__global__ void k_prep_xb(const float* __restrict__ x, const int* __restrict__ len,
                          short* __restrict__ xb) {
    for (size_t idx = (size_t)blockIdx.x * 256 + threadIdx.x; idx < SZ_XBF_S;
         idx += (size_t)gridDim.x * 256) {
        int j = (int)(idx & 7); size_t t = idx >> 3;
        int l = (int)(t & 63); t >>= 6;
        int hilo = (int)(t & 1); t >>= 1;
        int kt = (int)(t % 5); t /= 5;
        int nt = (int)(t & 3); t >>= 2;
        int kh = (int)(t & 1); t >>= 1;
        int dir = (int)(t & 1); t >>= 1;
        int s = (int)t;
        int b = nt * 16 + (l & 15);
        int k = kh * 160 + kt * 32 + kmap(l, j);
        float v = 0.f;
        if (k < I_) {
            int src = s;
            if (dir) { int L = len[b]; src = (s < L) ? (L - 1 - s) : s; }
            v = x[((size_t)b * S_ + src) * I_ + k];
        }
        unsigned u32 = __float_as_uint(v);
        float hi_f = __uint_as_float(u32 & 0xffff0000u);
        xb[idx] = hilo ? (short)(__float_as_uint(v - hi_f) >> 16)
                       : (short)(u32 >> 16);
    }
}

// ---------------- persistent BiLSTM scan: split-bf16 MFMA, LDS weights ----
// 256 blocks x 512 threads (cooperative for co-residency; NO grid.sync).
// Block = (dir, ug) owns units u=ug*4..+3 (one 16-row M-tile in permuted
// row space r' = uu*4+g). Wave wq = (nt = wq>>1: b-cols; kh = wq&1: K-half).
// WEIGHTS: A-fragments staged ONCE into LDS (frags are nt-independent ->
// 32 KB h + 20 KB x per block). Round 6's VGPR=128 allocation made the
// compiler RE-LOAD ah/al from global every step = 16.38 GB/dispatch fabric
// streaming (exact arithmetic match with FETCH_SIZE) -> the 9.5 ms pin.
// LDS residency removes that traffic structurally.
// x-phase: precomputed B-frags (coalesced dwordx4) + 15 MFMAs, pre-wait.
// h-phase: scattered y[s-1] loads + split + 24 MFMAs, post-wait.
// Sync/flag/y protocol identical to rounds 4-6.
__global__ __launch_bounds__(512, 2) void k_scan(
    const short* __restrict__ whf, const short* __restrict__ wxf,
    const short* __restrict__ xbf,
    float* yf, float* ybr,
    const float* __restrict__ bf, const float* __restrict__ bb,
    const int* __restrict__ len, int* __restrict__ flg)
{
    __shared__ bf16x8 hA[2 * 8 * 2 * 64];   // 32 KB  [kh][kt][hilo][lane]
    __shared__ bf16x8 xA[2 * 5 * 2 * 64];   // 20 KB  [kh][kt][hilo][lane]
    __shared__ float parts[32 * 66];        // 8.25 KB, stride-66 (bank-safe)
    const int dir = blockIdx.x >> 7;
    const int ug  = blockIdx.x & 127;
    const int tid = threadIdx.x;
    const int lane = tid & 63;
    const int wq = __builtin_amdgcn_readfirstlane(tid >> 6);  // 0..7
    const int nt = wq >> 1, kh = wq & 1;
    const int bcol = (nt << 4) + (lane & 15);

    // ---- stage A-fragments into LDS, once ----
    {
        const bf16x8* whp = (const bf16x8*)whf + (size_t)(dir * 128 + ug) * 2048;
        for (int i = tid; i < 2048; i += 512) hA[i] = whp[i];
        const bf16x8* wxp = (const bf16x8*)wxf + (size_t)(dir * 128 + ug) * 1280;
        for (int i = tid; i < 1280; i += 512) xA[i] = wxp[i];
    }

    float* ybase = dir ? ybr : yf;
    int* const myflag = flg + ((size_t)(dir * 128 + ug) << 4);
    // wave kh consumes u in [kh*256, kh*256+256) -> producers ug' = kh*64+lane
    const int* const fp = flg + ((size_t)(dir * 128 + kh * 64 + lane) << 4);

    // finalizer (waves 0..3 = uu) persistent state
    const int uF = (ug << 2) + wq;
    float c_reg = 0.f;
    float bi0 = 0.f, bi1 = 0.f, bi2 = 0.f, bi3 = 0.f;
    if (wq < 4) {
        const float* bias = dir ? bb : bf;
        bi0 = bias[uF]; bi1 = bias[H_ + uF];
        bi2 = bias[2 * H_ + uF]; bi3 = bias[3 * H_ + uF];
    }
    const int Lb = len[lane];

    int ko[8];
#pragma unroll
    for (int j = 0; j < 8; ++j) ko[j] = kmap(lane, j);

    __syncthreads();   // LDS A-frags ready

    for (int s = 0; s < S_; ++s) {
        f32x4 d = {0.f, 0.f, 0.f, 0.f};

        // ---- x-phase (h-independent, pre-wait): coalesced frag loads ----
        {
            const bf16x8* xb = (const bf16x8*)xbf +
                ((((size_t)(s * 2 + dir) * 2 + kh) * 4 + nt) * 5) * 2 * 64;
#pragma unroll
            for (int kt = 0; kt < 5; ++kt) {
                bf16x8 b_h = xb[(kt * 2 + 0) * 64 + lane];
                bf16x8 b_l = xb[(kt * 2 + 1) * 64 + lane];
                bf16x8 a_h = xA[((kh * 5 + kt) * 2 + 0) * 64 + lane];
                bf16x8 a_l = xA[((kh * 5 + kt) * 2 + 1) * 64 + lane];
                d = __builtin_amdgcn_mfma_f32_16x16x32_bf16(a_h, b_h, d, 0, 0, 0);
                d = __builtin_amdgcn_mfma_f32_16x16x32_bf16(a_h, b_l, d, 0, 0, 0);
                d = __builtin_amdgcn_mfma_f32_16x16x32_bf16(a_l, b_h, d, 0, 0, 0);
            }
        }

        // ---- wait: this wave's 64 producers must have flagged step s ----
        if (s) {
            for (;;) {
                int v = __hip_atomic_load(fp, __ATOMIC_RELAXED,
                                          __HIP_MEMORY_SCOPE_AGENT);
                if (__all(v >= s)) break;
                __builtin_amdgcn_s_sleep(1);
            }
        }
        asm volatile("" ::: "memory");

        // ---- h-phase: y[s-1] loads + split + MFMA (skip at s==0: h==0) ----
        if (s) {
            const float* hprev = ybase + ((size_t)(s - 1) << 15);   // H_*B_
#pragma unroll
            for (int kt = 0; kt < 8; ++kt) {
                const int k0 = kh * 256 + kt * 32;
                float hv[8];
#pragma unroll
                for (int j = 0; j < 8; ++j)
                    hv[j] = hprev[((size_t)(k0 + ko[j]) << 6) + bcol];
                bf16x8 b_h, b_l;
#pragma unroll
                for (int j = 0; j < 8; ++j) {
                    unsigned u32 = __float_as_uint(hv[j]);
                    b_h[j] = (short)(u32 >> 16);
                    float hi_f = __uint_as_float(u32 & 0xffff0000u);
                    b_l[j] = (short)(__float_as_uint(hv[j] - hi_f) >> 16);
                }
                bf16x8 a_h = hA[((kh * 8 + kt) * 2 + 0) * 64 + lane];
                bf16x8 a_l = hA[((kh * 8 + kt) * 2 + 1) * 64 + lane];
                d = __builtin_amdgcn_mfma_f32_16x16x32_bf16(a_h, b_h, d, 0, 0, 0);
                d = __builtin_amdgcn_mfma_f32_16x16x32_bf16(a_h, b_l, d, 0, 0, 0);
                d = __builtin_amdgcn_mfma_f32_16x16x32_bf16(a_l, b_h, d, 0, 0, 0);
            }
        }

        // ---- dump D (C/D layout: col=lane&15, row=(lane>>4)*4+reg) ----
        {
            const int m0 = (lane >> 4) << 2;
#pragma unroll
            for (int r = 0; r < 4; ++r)
                parts[(kh * 16 + m0 + r) * 66 + bcol] = d[r];
        }
        __syncthreads();

        if (wq < 4) {
            const int rb = wq << 2;   // m = uu*4 + g, uu = wq
            float g0 = bi0 + parts[(rb + 0) * 66 + lane] + parts[(16 + rb + 0) * 66 + lane];
            float g1 = bi1 + parts[(rb + 1) * 66 + lane] + parts[(16 + rb + 1) * 66 + lane];
            float g2 = bi2 + parts[(rb + 2) * 66 + lane] + parts[(16 + rb + 2) * 66 + lane];
            float g3 = bi3 + parts[(rb + 3) * 66 + lane] + parts[(16 + rb + 3) * 66 + lane];
            float ii = 1.f / (1.f + expf(-g0));
            float ff = 1.f / (1.f + expf(-g1));
            float gg = tanhf(g2);
            float oo = 1.f / (1.f + expf(-g3));
            float cn2 = ff * c_reg + ii * gg;
            float hn = oo * tanhf(cn2);
            c_reg = cn2;                       // post-length state is don't-care
            float yv = (s < Lb) ? hn : 0.f;
            __hip_atomic_store(&ybase[((size_t)(s * H_ + uF) << 6) + lane], yv,
                               __ATOMIC_RELAXED, __HIP_MEMORY_SCOPE_AGENT);
        }

        // drain y stores, block barrier, one flag store (no RMW).
        asm volatile("s_waitcnt vmcnt(0)" ::: "memory");
        __syncthreads();
        if (tid == 0)
            __hip_atomic_store(myflag, s + 1, __ATOMIC_RELAXED,
                               __HIP_MEMORY_SCOPE_AGENT);
    }
}

// ---------------- logits / CRF epilogue (unchanged, verified) ----------------
__global__ __launch_bounds__(256) void k_logits(const float* __restrict__ yf,
                                                const float* __restrict__ ybr,
                                                const float* __restrict__ wc,
                                                const float* __restrict__ bcv,
                                                float* __restrict__ L1,
                                                float* __restrict__ L2p) {
    __shared__ float smem[T_ * H_];
    int part = blockIdx.x >> 9;
    int s = blockIdx.x & 511;
    int tid = threadIdx.x;
    const float* y = part ? ybr : yf;
    float* Ldst = part ? L2p : L1;
    for (int idx = tid; idx < T_ * H_; idx += 256) {
        int t = idx >> 9;
        int h = idx & 511;
        smem[idx] = wc[(size_t)t * 1024 + part * 512 + h];
    }
    __syncthreads();
    int q = tid >> 6, b = tid & 63;
    float acc[T_];
#pragma unroll
    for (int t = 0; t < T_; ++t) acc[t] = 0.f;
    const float* yrow = y + (size_t)s * H_ * B_ + b;
    for (int h = q * 128; h < q * 128 + 128; ++h) {
        float a = yrow[(size_t)h * B_];
#pragma unroll
        for (int t = 0; t < T_; ++t) acc[t] += a * smem[t * H_ + h];
    }
    __syncthreads();
    float* pl = smem;
#pragma unroll
    for (int t = 0; t < T_; ++t) pl[(q * 64 + b) * 26 + t] = acc[t];
    __syncthreads();
    for (int idx = tid; idx < B_ * T_; idx += 256) {
        int bb2 = idx / T_;
        int t = idx - bb2 * T_;
        float v = pl[(0 * 64 + bb2) * 26 + t] + pl[(1 * 64 + bb2) * 26 + t] +
                  pl[(2 * 64 + bb2) * 26 + t] + pl[(3 * 64 + bb2) * 26 + t];
        if (!part) v += bcv[t];
        Ldst[((size_t)bb2 * S_ + s) * T_ + t] = v;
    }
}

__global__ void k_combine(const float* __restrict__ L1, const float* __restrict__ L2p,
                          const int* __restrict__ len, float* __restrict__ outlog) {
    int id = blockIdx.x * 256 + threadIdx.x;  // 32768 = B*S
    int b = id >> 9;
    int s = id & 511;
    int L = len[b];
    int sr = (s < L) ? (L - 1 - s) : s;
    const float* p1 = L1 + ((size_t)b * S_ + s) * T_;
    const float* p2 = L2p + ((size_t)b * S_ + sr) * T_;
    float* o = outlog + ((size_t)b * S_ + s) * T_;
#pragma unroll
    for (int t = 0; t < T_; ++t) o[t] = p1[t] + p2[t];
}

__global__ __launch_bounds__(64) void k_crf_nll(const float* __restrict__ em,
                                                const int* __restrict__ labels,
                                                const int* __restrict__ len,
                                                const float* __restrict__ cs,
                                                const float* __restrict__ ce,
                                                const float* __restrict__ ctr,
                                                float* __restrict__ llh) {
    int b = blockIdx.x, tid = threadIdx.x;
    __shared__ float tr[T_ * T_];
    __shared__ float sa[T_], sb[T_];
    for (int idx = tid; idx < T_ * T_; idx += 64) tr[idx] = ctr[idx];
    const float* e = em + (size_t)b * S_ * T_;
    int L = len[b];
    if (tid < T_) sa[tid] = cs[tid] + e[tid];
    __syncthreads();
    float* cur = sa;
    float* nx = sb;
    for (int t = 1; t < L; ++t) {
        if (tid < T_) {
            float m = -1e30f;
            for (int i = 0; i < T_; ++i) m = fmaxf(m, cur[i] + tr[i * T_ + tid]);
            float ssum = 0.f;
            for (int i = 0; i < T_; ++i) ssum += expf(cur[i] + tr[i * T_ + tid] - m);
            nx[tid] = m + logf(ssum) + e[(size_t)t * T_ + tid];
        }
        __syncthreads();
        float* tmp = cur; cur = nx; nx = tmp;
    }
    float part = 0.f;
    for (int t = tid; t < S_; t += 64) {
        if (t >= 1 && t < L) {
            int lp = labels[b * S_ + t - 1];
            int lc = labels[b * S_ + t];
            part += tr[lp * T_ + lc] + e[(size_t)t * T_ + lc];
        }
    }
    for (int off = 32; off; off >>= 1) part += __shfl_down(part, off, 64);
    if (tid == 0) {
        float m = -1e30f;
        for (int j = 0; j < T_; ++j) m = fmaxf(m, cur[j] + ce[j]);
        float ssum = 0.f;
        for (int j = 0; j < T_; ++j) ssum += expf(cur[j] + ce[j] - m);
        float denom = m + logf(ssum);
        int l0 = labels[b * S_];
        int lL = labels[b * S_ + L - 1];
        float num = cs[l0] + e[l0] + part + ce[lL];
        llh[b] = num - denom;
    }
}

__global__ void k_loss(const float* __restrict__ llh, const int* __restrict__ len,
                       float* __restrict__ out0) {
    int tid = threadIdx.x;
    float v = llh[tid];
    float n = (float)len[tid];
    for (int off = 32; off; off >>= 1) {
        v += __shfl_down(v, off, 64);
        n += __shfl_down(n, off, 64);
    }
    if (tid == 0) out0[0] = -(v / n);
}

__global__ __launch_bounds__(64) void k_viterbi(const float* __restrict__ em,
                                                const int* __restrict__ len,
                                                const float* __restrict__ cs,
                                                const float* __restrict__ ce,
                                                const float* __restrict__ ctr,
                                                float* __restrict__ otags,
                                                float* __restrict__ omask) {
    int b = blockIdx.x, tid = threadIdx.x;
    __shared__ float tr[T_ * T_];
    __shared__ float sa[T_], sb[T_];
    __shared__ unsigned char hist[(S_ - 1) * T_];
    __shared__ unsigned char tg[S_];
    for (int idx = tid; idx < T_ * T_; idx += 64) tr[idx] = ctr[idx];
    const float* e = em + (size_t)b * S_ * T_;
    int L = len[b];
    if (tid < T_) sa[tid] = cs[tid] + e[tid];
    __syncthreads();
    float* cur = sa;
    float* nx = sb;
    for (int t = 1; t < L; ++t) {
        if (tid < T_) {
            float best = -1e30f;
            int bi = 0;
            for (int i = 0; i < T_; ++i) {
                float v = cur[i] + tr[i * T_ + tid];
                if (v > best) { best = v; bi = i; }
            }
            nx[tid] = best + e[(size_t)t * T_ + tid];
            hist[(t - 1) * T_ + tid] = (unsigned char)bi;
        }
        __syncthreads();
        float* tmp = cur; cur = nx; nx = tmp;
    }
    if (tid == 0) {
        float best = -1e30f;
        int bt = 0;
        for (int j = 0; j < T_; ++j) {
            float v = cur[j] + ce[j];
            if (v > best) { best = v; bt = j; }
        }
        tg[S_ - 1] = (unsigned char)bt;
        for (int t = S_ - 2; t >= 0; --t) {
            if (t + 1 < L) bt = hist[t * T_ + bt];
            tg[t] = (unsigned char)bt;
        }
    }
    __syncthreads();
    for (int idx = tid; idx < S_; idx += 64) {
        otags[(size_t)b * S_ + idx] = (float)tg[idx];
        omask[(size_t)b * S_ + idx] = (idx < L) ? 1.f : 0.f;
    }
}

// ---------------- host launch ----------------
extern "C" void kernel_launch(void* const* d_in, const int* in_sizes, int n_in,
                              void* d_out, int out_size, void* d_ws, size_t ws_size,
                              hipStream_t stream) {
    const float* x    = (const float*)d_in[0];
    const float* wihf = (const float*)d_in[1];
    const float* whhf = (const float*)d_in[2];
    const float* bf   = (const float*)d_in[3];
    const float* wihb = (const float*)d_in[4];
    const float* whhb = (const float*)d_in[5];
    const float* bb   = (const float*)d_in[6];
    const float* wc   = (const float*)d_in[7];
    const float* bc   = (const float*)d_in[8];
    const float* cs   = (const float*)d_in[9];
    const float* ce   = (const float*)d_in[10];
    const float* ctr  = (const float*)d_in[11];
    const int* am     = (const int*)d_in[12];
    const int* labels = (const int*)d_in[13];

    float* ws   = (float*)d_ws;
    short* xbfr = (short*)(ws + OFS_XBF);
    short* whfr = (short*)(ws + OFS_WHF);
    short* wxfr = (short*)(ws + OFS_WXF);
    float* yf   = ws + OFS_YF;
    float* ybr  = ws + OFS_YB;
    float* L1p  = ws + OFS_L1;
    float* L2p  = ws + OFS_L2;
    int*   lenp = (int*)(ws + OFS_LEN);
    float* llhp = ws + OFS_LLH;
    int*   flgp = (int*)(ws + OFS_FLG);
    float* out  = (float*)d_out;

    k_lengths<<<1, 64, 0, stream>>>(am, lenp);
    k_prep_hfrag<<<2048, 256, 0, stream>>>(whhf, whhb, whfr);
    k_prep_xfrag<<<2048, 256, 0, stream>>>(wihf, wihb, wxfr);
    k_prep_xb<<<8192, 256, 0, stream>>>(x, lenp, xbfr);
    k_zero<<<16, 256, 0, stream>>>(ws + OFS_FLG, 2 * 128 * 16);  // flags

    {
        void* kargs[] = {
            (void*)&whfr, (void*)&wxfr, (void*)&xbfr,
            (void*)&yf, (void*)&ybr,
            (void*)&bf, (void*)&bb,
            (void*)&lenp, (void*)&flgp
        };
        hipLaunchCooperativeKernel((const void*)k_scan,
                                   dim3(256), dim3(512), kargs, 0, stream);
    }

    k_logits<<<1024, 256, 0, stream>>>(yf, ybr, wc, bc, L1p, L2p);
    k_combine<<<128, 256, 0, stream>>>(L1p, L2p, lenp, out + OFF_LOGITS);
    k_crf_nll<<<64, 64, 0, stream>>>(out + OFF_LOGITS, labels, lenp, cs, ce, ctr, llhp);
    k_loss<<<1, 64, 0, stream>>>(llhp, lenp, out);
    k_viterbi<<<64, 64, 0, stream>>>(out + OFF_LOGITS, lenp, cs, ce, ctr,
                                     out + OFF_TAGS, out + OFF_MASK);
}